// Round 2
// baseline (164.086 us; speedup 1.0000x reference)
//
#include <hip/hip_runtime.h>

// ---------------------------------------------------------------------------
// DeepLagrangianNetwork head, MFMA version — round 6 (4 rows/thread).
// Round-5 post-mortem: removing 40% of VALU work changed nothing -> kernel is
// LATENCY-bound (per-SIMD VALU util ~19%, all pipes idle). This round
// amortizes per-wave latency: each thread handles 4 rows (1024 rows/block,
// grid = 1024 blocks = exactly 4 blocks/CU, all resident, one generation).
//   per row: h1 = lrelu(q@W1^T+b1)  (4->64, VALU, v_cvt_pk_bf16 packing)
//            h2^T = W2 @ h1^T       (bf16 MFMA 16x16x32, A = W2 tiles)
//            heads (Ld, Lo) on fp32 h2 in-register, quad-reduced via shfl_xor
//            H = L L^T + 1e-9 I (2x2), one coalesced float4 store per row.
// Zero __syncthreads: all cross-lane traffic is intra-wave (LDS + shuffles).
// LDS h1 buffer [wave][ch][row][8 bf16] = 8 KiB/wave, REUSED across the 4
// row-groups — safe because per-wave DS ops execute in order (write g+1 is
// issued after reads of g in the same wave's program order).
// Fragment layouts (m89/m120-verified):
//   A[m=lane&15][k=(lane>>4)*8+j]   B[k=(lane>>4)*8+j][n=lane&15]
//   C: col(n)=lane&15, row(m)=(lane>>4)*4+reg
//   mfma(Xf,Yf) = X·Y^T; X=W2 m-tile, Y=h1 row-tile => C[m=neuron][n=row].
// ---------------------------------------------------------------------------

typedef __attribute__((ext_vector_type(8))) short bf16x8;
typedef __attribute__((ext_vector_type(4))) float f32x4;

#define ROWS_PER_BLOCK 1024     // 4 row-groups of 256
#define G_ITERS 4

__device__ __forceinline__ float lrelu(float a) {
    return fmaxf(a, 0.01f * a);     // exact leaky_relu(0.01)
}

__device__ __forceinline__ float softplus(float v) {
    return fmaxf(v, 0.0f) + log1pf(expf(-fabsf(v)));   // jax.nn.softplus
}

// two fp32 -> packed bf16x2 (hardware RNE), 1 VALU op.
__device__ __forceinline__ unsigned cvt_pk_bf16(float lo, float hi) {
    unsigned r;
    asm("v_cvt_pk_bf16_f32 %0, %1, %2" : "=v"(r) : "v"(lo), "v"(hi));
    return r;
}

__global__ __launch_bounds__(256, 4) void dln_mfma(
    const float* __restrict__ x,
    const float* __restrict__ W1,  const float* __restrict__ b1,
    const float* __restrict__ W2,  const float* __restrict__ b2,
    const float* __restrict__ WLd, const float* __restrict__ bLd,
    const float* __restrict__ WLo, const float* __restrict__ bLo,
    float* __restrict__ out)
{
    __shared__ __align__(16) unsigned short h1s[4][8][64][8];   // 8 KiB/wave

    const int tid  = threadIdx.x;
    const int lane = tid & 63;
    const int wv   = tid >> 6;          // wave id 0..3
    const int quad = lane >> 4;         // 0..3
    const int c    = lane & 15;         // 0..15

    // ---- x loads first: 4 independent float4 loads, all in flight --------
    const int row0 = blockIdx.x * ROWS_PER_BLOCK + tid;   // group stride 256
    const float4 qv0 = ((const float4*)x)[row0];
    const float4 qv1 = ((const float4*)x)[row0 + 256];
    const float4 qv2 = ((const float4*)x)[row0 + 512];
    const float4 qv3 = ((const float4*)x)[row0 + 768];

    // ---- preload (once per block, amortized over 4 row-groups):
    //      A-frags = W2 tiles (bf16), head weights + b2 (fp32, lane-indexed)
    bf16x8 afrag[4][2];
    f32x4 wld0[4], wld1[4], wlo[4], b2v[4];
#pragma unroll
    for (int mt = 0; mt < 4; ++mt) {
        const float* wr = W2 + (16 * mt + c) * 64 + 8 * quad;
#pragma unroll
        for (int s = 0; s < 2; ++s) {
            const float4 f0 = *(const float4*)(wr + 32 * s);
            const float4 f1 = *(const float4*)(wr + 32 * s + 4);
            uint4 u;
            u.x = cvt_pk_bf16(f0.x, f0.y);
            u.y = cvt_pk_bf16(f0.z, f0.w);
            u.z = cvt_pk_bf16(f1.x, f1.y);
            u.w = cvt_pk_bf16(f1.z, f1.w);
            afrag[mt][s] = __builtin_bit_cast(bf16x8, u);
        }
        const int nb = 16 * mt + 4 * quad;   // this lane's 16 neurons
        wld0[mt] = *(const f32x4*)(WLd + nb);
        wld1[mt] = *(const f32x4*)(WLd + 64 + nb);
        wlo[mt]  = *(const f32x4*)(WLo + nb);
        b2v[mt]  = *(const f32x4*)(b2 + nb);
    }
    const float bld0 = bLd[0];
    const float bld1 = bLd[1];
    const float blo0 = bLo[0];

#pragma unroll
    for (int g = 0; g < G_ITERS; ++g) {
        const float4 qv = (g == 0) ? qv0 : (g == 1) ? qv1 : (g == 2) ? qv2 : qv3;
        const int row_g = row0 + g * 256;

        // ---- phase 1: h1 = lrelu(q@W1^T + b1), bf16 -> LDS (own slot) ----
#pragma unroll
        for (int ch = 0; ch < 8; ++ch) {        // chunk ch holds k=8ch..8ch+7
            unsigned up[4];
#pragma unroll
            for (int p = 0; p < 4; ++p) {
                float h[2];
#pragma unroll
                for (int e = 0; e < 2; ++e) {
                    const int j = ch * 8 + p * 2 + e;
                    float a = b1[j];
                    a = fmaf(qv.x, W1[4 * j + 0], a);
                    a = fmaf(qv.y, W1[4 * j + 1], a);
                    a = fmaf(qv.z, W1[4 * j + 2], a);
                    a = fmaf(qv.w, W1[4 * j + 3], a);
                    h[e] = lrelu(a);
                }
                up[p] = cvt_pk_bf16(h[0], h[1]);
            }
            *(uint4*)&h1s[wv][ch][lane][0] = make_uint4(up[0], up[1], up[2], up[3]);
        }
        // No barrier: this wave reads only rows it wrote; per-wave DS ops
        // execute in order (also makes buffer reuse across g safe).

        // ---- phase 2: h2^T tiles via MFMA; heads in-register -------------
        float sld0 = 0.0f, sld1 = 0.0f, slo = 0.0f;
#pragma unroll
        for (int it = 0; it < 4; ++it) {            // 16 batch rows / iter
            const bf16x8 bf0 = *(const bf16x8*)&h1s[wv][quad][it * 16 + c][0];
            const bf16x8 bf1 = *(const bf16x8*)&h1s[wv][4 + quad][it * 16 + c][0];

            float pld0 = 0.0f, pld1 = 0.0f, plo = 0.0f;
#pragma unroll
            for (int mt = 0; mt < 4; ++mt) {
                f32x4 acc = b2v[mt];                // bias pre-load
                acc = __builtin_amdgcn_mfma_f32_16x16x32_bf16(afrag[mt][0], bf0, acc, 0, 0, 0);
                acc = __builtin_amdgcn_mfma_f32_16x16x32_bf16(afrag[mt][1], bf1, acc, 0, 0, 0);
#pragma unroll
                for (int r = 0; r < 4; ++r) {
                    const float h2 = lrelu(acc[r]); // fp32 h2, never rounded
                    pld0 = fmaf(h2, wld0[mt][r], pld0);
                    pld1 = fmaf(h2, wld1[mt][r], pld1);
                    plo  = fmaf(h2, wlo[mt][r],  plo);
                }
            }
            // reduce partials over the 4 quads (disjoint neuron subsets)
            pld0 += __shfl_xor(pld0, 16); pld0 += __shfl_xor(pld0, 32);
            pld1 += __shfl_xor(pld1, 16); pld1 += __shfl_xor(pld1, 32);
            plo  += __shfl_xor(plo,  16); plo  += __shfl_xor(plo,  32);
            // lane(q,c) keeps iteration it==q -> its own row (= lane)
            if (it == quad) { sld0 = pld0; sld1 = pld1; slo = plo; }
        }

        // ---- epilogue: one row per lane, fully coalesced store -----------
        {
            const float ld0 = softplus(sld0 + bld0);
            const float ld1 = softplus(sld1 + bld1);
            const float lo  = slo + blo0;
            float4 o;
            o.x = fmaf(ld0, ld0, 1e-9f);                  // H00
            o.y = ld0 * lo;                               // H01
            o.z = o.y;                                    // H10
            o.w = fmaf(lo, lo, fmaf(ld1, ld1, 1e-9f));    // H11
            reinterpret_cast<float4*>(out)[row_g] = o;
        }
    }
}

// ---- scalar fallback for tail rows (nrows % 1024) -------------------------
__global__ __launch_bounds__(256) void dln_tail(
    const float* __restrict__ x,
    const float* __restrict__ W1,  const float* __restrict__ b1,
    const float* __restrict__ W2,  const float* __restrict__ b2,
    const float* __restrict__ WLd, const float* __restrict__ bLd,
    const float* __restrict__ WLo, const float* __restrict__ bLo,
    float* __restrict__ out, int row0, int nrows)
{
    const int row = row0 + blockIdx.x * 256 + threadIdx.x;
    if (row >= nrows) return;
    const float4 qv = reinterpret_cast<const float4*>(x)[row];
    float h1[64];
#pragma unroll
    for (int j = 0; j < 64; ++j) {
        float a = b1[j];
        a = fmaf(qv.x, W1[4 * j + 0], a);
        a = fmaf(qv.y, W1[4 * j + 1], a);
        a = fmaf(qv.z, W1[4 * j + 2], a);
        a = fmaf(qv.w, W1[4 * j + 3], a);
        h1[j] = lrelu(a);
    }
    float ld0 = bLd[0], ld1 = bLd[1], lo = bLo[0];
#pragma unroll 4
    for (int j = 0; j < 64; ++j) {
        float a0 = b2[j], a1 = 0.0f;
        const float* w = W2 + 64 * j;
#pragma unroll
        for (int k = 0; k < 64; k += 2) {
            a0 = fmaf(h1[k],     w[k],     a0);
            a1 = fmaf(h1[k + 1], w[k + 1], a1);
        }
        const float a = lrelu(a0 + a1);
        ld0 = fmaf(a, WLd[j],      ld0);
        ld1 = fmaf(a, WLd[64 + j], ld1);
        lo  = fmaf(a, WLo[j],      lo);
    }
    ld0 = softplus(ld0);
    ld1 = softplus(ld1);
    float4 o;
    o.x = fmaf(ld0, ld0, 1e-9f);
    o.y = ld0 * lo;
    o.z = o.y;
    o.w = fmaf(lo, lo, fmaf(ld1, ld1, 1e-9f));
    reinterpret_cast<float4*>(out)[row] = o;
}

extern "C" void kernel_launch(void* const* d_in, const int* in_sizes, int n_in,
                              void* d_out, int out_size, void* d_ws, size_t ws_size,
                              hipStream_t stream)
{
    const float* x   = (const float*)d_in[0];
    const float* W1  = (const float*)d_in[1];
    const float* b1  = (const float*)d_in[2];
    const float* W2  = (const float*)d_in[3];
    const float* b2  = (const float*)d_in[4];
    const float* WLd = (const float*)d_in[5];
    const float* bLd = (const float*)d_in[6];
    const float* WLo = (const float*)d_in[7];
    const float* bLo = (const float*)d_in[8];
    float* out = (float*)d_out;

    const int nrows = in_sizes[0] / 4;             // x is (nrows, 4) fp32
    const int nfull = nrows / ROWS_PER_BLOCK;
    const int rem   = nrows - nfull * ROWS_PER_BLOCK;

    if (nfull > 0)
        dln_mfma<<<nfull, 256, 0, stream>>>(
            x, W1, b1, W2, b2, WLd, bLd, WLo, bLo, out);
    if (rem > 0)
        dln_tail<<<(rem + 255) / 256, 256, 0, stream>>>(
            x, W1, b1, W2, b2, WLd, bLd, WLo, bLo, out,
            nfull * ROWS_PER_BLOCK, nrows);
}

// Round 3
// 123.713 us; speedup vs baseline: 1.3263x; 1.3263x over previous
//
#include <hip/hip_runtime.h>

// ---------------------------------------------------------------------------
// DeepLagrangianNetwork head, MFMA version — round 7 (2 rows/thread, 2-wave
// blocks). Round-6 post-mortem: 4 rows/thread + __launch_bounds__(256,4)
// made the allocator pin 64 VGPRs and spill ~1KB/thread to scratch
// (FETCH 8->158 MB). Same latency-amortization theory, spill-proof sizing:
//   - 2 row-groups/thread (qv pair = +4 VGPRs only), no occupancy hint
//   - 128-thread blocks (2 waves), 16 KiB LDS, 256 rows/block, grid 4096
//   - zero __syncthreads (wave-self-contained; LDS reuse across groups is
//     safe because per-wave DS ops execute in program order)
// Per row: h1 = lrelu(q@W1^T+b1)  (4->64, VALU, v_cvt_pk_bf16 packing)
//          h2^T = W2 @ h1^T       (bf16 MFMA 16x16x32, A = W2 tiles)
//          heads (Ld, Lo) on fp32 h2 in-register, quad-reduced via shfl_xor
//          H = L L^T + 1e-9 I (2x2), one coalesced float4 store per row.
// Fragment layouts (m89/m120-verified):
//   A[m=lane&15][k=(lane>>4)*8+j]   B[k=(lane>>4)*8+j][n=lane&15]
//   C: col(n)=lane&15, row(m)=(lane>>4)*4+reg
//   mfma(Xf,Yf) = X·Y^T; X=W2 m-tile, Y=h1 row-tile => C[m=neuron][n=row].
// ---------------------------------------------------------------------------

typedef __attribute__((ext_vector_type(8))) short bf16x8;
typedef __attribute__((ext_vector_type(4))) float f32x4;

#define BLOCK_THREADS 128       // 2 waves
#define ROWS_PER_BLOCK 256      // 2 groups x 128 rows
#define G_ITERS 2

__device__ __forceinline__ float lrelu(float a) {
    return fmaxf(a, 0.01f * a);     // exact leaky_relu(0.01)
}

__device__ __forceinline__ float softplus(float v) {
    return fmaxf(v, 0.0f) + log1pf(expf(-fabsf(v)));   // jax.nn.softplus
}

// two fp32 -> packed bf16x2 (hardware RNE), 1 VALU op.
__device__ __forceinline__ unsigned cvt_pk_bf16(float lo, float hi) {
    unsigned r;
    asm("v_cvt_pk_bf16_f32 %0, %1, %2" : "=v"(r) : "v"(lo), "v"(hi));
    return r;
}

__global__ __launch_bounds__(BLOCK_THREADS) void dln_mfma(
    const float* __restrict__ x,
    const float* __restrict__ W1,  const float* __restrict__ b1,
    const float* __restrict__ W2,  const float* __restrict__ b2,
    const float* __restrict__ WLd, const float* __restrict__ bLd,
    const float* __restrict__ WLo, const float* __restrict__ bLo,
    float* __restrict__ out)
{
    __shared__ __align__(16) unsigned short h1s[2][8][64][8];   // 16 KiB

    const int tid  = threadIdx.x;
    const int lane = tid & 63;
    const int wv   = tid >> 6;          // wave id 0..1
    const int quad = lane >> 4;         // 0..3
    const int c    = lane & 15;         // 0..15

    // ---- x loads first: both groups' float4 in flight ---------------------
    const int row0 = blockIdx.x * ROWS_PER_BLOCK + tid;     // group stride 128
    float4 qv[G_ITERS];
    qv[0] = ((const float4*)x)[row0];
    qv[1] = ((const float4*)x)[row0 + 128];

    // ---- preload (once per block, amortized over 2 row-groups):
    //      A-frags = W2 tiles (bf16), head weights + b2 (fp32, lane-indexed)
    bf16x8 afrag[4][2];
    f32x4 wld0[4], wld1[4], wlo[4], b2v[4];
#pragma unroll
    for (int mt = 0; mt < 4; ++mt) {
        const float* wr = W2 + (16 * mt + c) * 64 + 8 * quad;
#pragma unroll
        for (int s = 0; s < 2; ++s) {
            const float4 f0 = *(const float4*)(wr + 32 * s);
            const float4 f1 = *(const float4*)(wr + 32 * s + 4);
            uint4 u;
            u.x = cvt_pk_bf16(f0.x, f0.y);
            u.y = cvt_pk_bf16(f0.z, f0.w);
            u.z = cvt_pk_bf16(f1.x, f1.y);
            u.w = cvt_pk_bf16(f1.z, f1.w);
            afrag[mt][s] = __builtin_bit_cast(bf16x8, u);
        }
        const int nb = 16 * mt + 4 * quad;   // this lane's 16 neurons
        wld0[mt] = *(const f32x4*)(WLd + nb);
        wld1[mt] = *(const f32x4*)(WLd + 64 + nb);
        wlo[mt]  = *(const f32x4*)(WLo + nb);
        b2v[mt]  = *(const f32x4*)(b2 + nb);
    }
    const float bld0 = bLd[0];
    const float bld1 = bLd[1];
    const float blo0 = bLo[0];

#pragma unroll
    for (int g = 0; g < G_ITERS; ++g) {
        const int row_g = row0 + g * 128;

        // ---- phase 1: h1 = lrelu(q@W1^T + b1), bf16 -> LDS (own slot) ----
#pragma unroll
        for (int ch = 0; ch < 8; ++ch) {        // chunk ch holds k=8ch..8ch+7
            unsigned up[4];
#pragma unroll
            for (int p = 0; p < 4; ++p) {
                float h[2];
#pragma unroll
                for (int e = 0; e < 2; ++e) {
                    const int j = ch * 8 + p * 2 + e;
                    float a = b1[j];
                    a = fmaf(qv[g].x, W1[4 * j + 0], a);
                    a = fmaf(qv[g].y, W1[4 * j + 1], a);
                    a = fmaf(qv[g].z, W1[4 * j + 2], a);
                    a = fmaf(qv[g].w, W1[4 * j + 3], a);
                    h[e] = lrelu(a);
                }
                up[p] = cvt_pk_bf16(h[0], h[1]);
            }
            *(uint4*)&h1s[wv][ch][lane][0] = make_uint4(up[0], up[1], up[2], up[3]);
        }
        // No barrier: this wave reads only rows it wrote; per-wave DS ops
        // execute in order (also makes buffer reuse across g safe).

        // ---- phase 2: h2^T tiles via MFMA; heads in-register -------------
        float sld0 = 0.0f, sld1 = 0.0f, slo = 0.0f;
#pragma unroll
        for (int it = 0; it < 4; ++it) {            // 16 batch rows / iter
            const bf16x8 bf0 = *(const bf16x8*)&h1s[wv][quad][it * 16 + c][0];
            const bf16x8 bf1 = *(const bf16x8*)&h1s[wv][4 + quad][it * 16 + c][0];

            float pld0 = 0.0f, pld1 = 0.0f, plo = 0.0f;
#pragma unroll
            for (int mt = 0; mt < 4; ++mt) {
                f32x4 acc = b2v[mt];                // bias pre-load
                acc = __builtin_amdgcn_mfma_f32_16x16x32_bf16(afrag[mt][0], bf0, acc, 0, 0, 0);
                acc = __builtin_amdgcn_mfma_f32_16x16x32_bf16(afrag[mt][1], bf1, acc, 0, 0, 0);
#pragma unroll
                for (int r = 0; r < 4; ++r) {
                    const float h2 = lrelu(acc[r]); // fp32 h2, never rounded
                    pld0 = fmaf(h2, wld0[mt][r], pld0);
                    pld1 = fmaf(h2, wld1[mt][r], pld1);
                    plo  = fmaf(h2, wlo[mt][r],  plo);
                }
            }
            // reduce partials over the 4 quads (disjoint neuron subsets)
            pld0 += __shfl_xor(pld0, 16); pld0 += __shfl_xor(pld0, 32);
            pld1 += __shfl_xor(pld1, 16); pld1 += __shfl_xor(pld1, 32);
            plo  += __shfl_xor(plo,  16); plo  += __shfl_xor(plo,  32);
            // lane(q,c) keeps iteration it==q -> its own row (= lane)
            if (it == quad) { sld0 = pld0; sld1 = pld1; slo = plo; }
        }

        // ---- epilogue: one row per lane, fully coalesced store -----------
        {
            const float ld0 = softplus(sld0 + bld0);
            const float ld1 = softplus(sld1 + bld1);
            const float lo  = slo + blo0;
            float4 o;
            o.x = fmaf(ld0, ld0, 1e-9f);                  // H00
            o.y = ld0 * lo;                               // H01
            o.z = o.y;                                    // H10
            o.w = fmaf(lo, lo, fmaf(ld1, ld1, 1e-9f));    // H11
            reinterpret_cast<float4*>(out)[row_g] = o;
        }
    }
}

// ---- scalar fallback for tail rows (nrows % 256) --------------------------
__global__ __launch_bounds__(256) void dln_tail(
    const float* __restrict__ x,
    const float* __restrict__ W1,  const float* __restrict__ b1,
    const float* __restrict__ W2,  const float* __restrict__ b2,
    const float* __restrict__ WLd, const float* __restrict__ bLd,
    const float* __restrict__ WLo, const float* __restrict__ bLo,
    float* __restrict__ out, int row0, int nrows)
{
    const int row = row0 + blockIdx.x * 256 + threadIdx.x;
    if (row >= nrows) return;
    const float4 qv = reinterpret_cast<const float4*>(x)[row];
    float h1[64];
#pragma unroll
    for (int j = 0; j < 64; ++j) {
        float a = b1[j];
        a = fmaf(qv.x, W1[4 * j + 0], a);
        a = fmaf(qv.y, W1[4 * j + 1], a);
        a = fmaf(qv.z, W1[4 * j + 2], a);
        a = fmaf(qv.w, W1[4 * j + 3], a);
        h1[j] = lrelu(a);
    }
    float ld0 = bLd[0], ld1 = bLd[1], lo = bLo[0];
#pragma unroll 4
    for (int j = 0; j < 64; ++j) {
        float a0 = b2[j], a1 = 0.0f;
        const float* w = W2 + 64 * j;
#pragma unroll
        for (int k = 0; k < 64; k += 2) {
            a0 = fmaf(h1[k],     w[k],     a0);
            a1 = fmaf(h1[k + 1], w[k + 1], a1);
        }
        const float a = lrelu(a0 + a1);
        ld0 = fmaf(a, WLd[j],      ld0);
        ld1 = fmaf(a, WLd[64 + j], ld1);
        lo  = fmaf(a, WLo[j],      lo);
    }
    ld0 = softplus(ld0);
    ld1 = softplus(ld1);
    float4 o;
    o.x = fmaf(ld0, ld0, 1e-9f);
    o.y = ld0 * lo;
    o.z = o.y;
    o.w = fmaf(lo, lo, fmaf(ld1, ld1, 1e-9f));
    reinterpret_cast<float4*>(out)[row] = o;
}

extern "C" void kernel_launch(void* const* d_in, const int* in_sizes, int n_in,
                              void* d_out, int out_size, void* d_ws, size_t ws_size,
                              hipStream_t stream)
{
    const float* x   = (const float*)d_in[0];
    const float* W1  = (const float*)d_in[1];
    const float* b1  = (const float*)d_in[2];
    const float* W2  = (const float*)d_in[3];
    const float* b2  = (const float*)d_in[4];
    const float* WLd = (const float*)d_in[5];
    const float* bLd = (const float*)d_in[6];
    const float* WLo = (const float*)d_in[7];
    const float* bLo = (const float*)d_in[8];
    float* out = (float*)d_out;

    const int nrows = in_sizes[0] / 4;             // x is (nrows, 4) fp32
    const int nfull = nrows / ROWS_PER_BLOCK;
    const int rem   = nrows - nfull * ROWS_PER_BLOCK;

    if (nfull > 0)
        dln_mfma<<<nfull, BLOCK_THREADS, 0, stream>>>(
            x, W1, b1, W2, b2, WLd, bLd, WLo, bLo, out);
    if (rem > 0)
        dln_tail<<<(rem + 255) / 256, 256, 0, stream>>>(
            x, W1, b1, W2, b2, WLd, bLd, WLo, bLo, out,
            nfull * ROWS_PER_BLOCK, nrows);
}